// Round 1
// 694.541 us; speedup vs baseline: 1.0047x; 1.0047x over previous
//
#include <hip/hip_runtime.h>
#include <hip/hip_bf16.h>
#include <cstdint>
#include <cstddef>

#define TOKENS 4096
#define HIDDEN 2048
#define INTER  1408
#define NE     8
#define NGU    2816            // 2*INTER (gate | up, 16-col interleaved)
#define CAP_ROWS 9216          // >= 8192 assignments + 8*127 tile pad

typedef __bf16 bf16;
typedef __bf16 bf16x8 __attribute__((ext_vector_type(8)));
typedef float  f32x4  __attribute__((ext_vector_type(4)));

__device__ __forceinline__ void async16(const void* g, void* l) {
  __builtin_amdgcn_global_load_lds((const __attribute__((address_space(1))) void*)g,
                                   (__attribute__((address_space(3))) void*)l,
                                   16, 0, 0);
}

// ---------------- router: logits, top-2, renorm weights; also x -> bf16 ----------------
__global__ void router_kernel(const float* __restrict__ x, const float* __restrict__ rw,
                              bf16* __restrict__ xb, int* __restrict__ cnt,
                              int* __restrict__ tok, float* __restrict__ wts) {
  const int w = threadIdx.x >> 6, l = threadIdx.x & 63;
  const int t = blockIdx.x * 4 + w;
  const float4* x4 = (const float4*)(x + (size_t)t * HIDDEN);
  const float4* r4 = (const float4*)rw;
  float acc[NE];
#pragma unroll
  for (int e = 0; e < NE; ++e) acc[e] = 0.f;
#pragma unroll
  for (int c = 0; c < 8; ++c) {
    const int idx = c * 64 + l;
    const float4 v = x4[idx];
    bf16* dst = xb + (size_t)t * HIDDEN + idx * 4;
    dst[0] = (bf16)v.x; dst[1] = (bf16)v.y; dst[2] = (bf16)v.z; dst[3] = (bf16)v.w;
#pragma unroll
    for (int e = 0; e < NE; ++e) {
      const float4 u = r4[e * 512 + idx];
      acc[e] += v.x * u.x + v.y * u.y + v.z * u.z + v.w * u.w;
    }
  }
#pragma unroll
  for (int e = 0; e < NE; ++e)
#pragma unroll
    for (int s = 32; s > 0; s >>= 1) acc[e] += __shfl_xor(acc[e], s, 64);
  if (l == 0) {
    int i0 = 0; float l0 = acc[0];
#pragma unroll
    for (int e = 1; e < NE; ++e) if (acc[e] > l0) { l0 = acc[e]; i0 = e; }
    int i1 = -1; float l1 = -3.4e38f;
#pragma unroll
    for (int e = 0; e < NE; ++e) if (e != i0 && acc[e] > l1) { l1 = acc[e]; i1 = e; }
    // renormalized top-2 softmax == softmax over the two top logits
    const float w0 = 1.f / (1.f + __expf(l1 - l0));
    const float w1 = 1.f - w0;
    int p = atomicAdd(&cnt[i0], 1); tok[i0 * 4096 + p] = t; wts[i0 * 4096 + p] = w0;
    p = atomicAdd(&cnt[i1], 1);     tok[i1 * 4096 + p] = t; wts[i1 * 4096 + p] = w1;
  }
}

// ---------------- 128-aligned exclusive scan of expert counts (8 entries) ----------------
__global__ void scan_kernel(const int* __restrict__ cnt, int* __restrict__ offs) {
  if (threadIdx.x == 0 && blockIdx.x == 0) {
    int o = 0;
    for (int e = 0; e < NE; ++e) { offs[e] = o; o += ((cnt[e] + 127) >> 7) << 7; }
    offs[NE] = o;
  }
}

// ---------------- 64x64 tiled transpose + fp32->bf16 ----------------
// in[R][C] fp32 -> out[p(c)][R] bf16.  mode 0: p=c (w_down)
// mode 1: gate -> p = (c/16)*32 + c%16 ; mode 2: up -> p = (c/16)*32 + 16 + c%16
__global__ __launch_bounds__(256) void transpose64(
    const float* __restrict__ in, bf16* __restrict__ out, int R, int C,
    size_t inSlab, size_t outSlab, int mode) {
  __shared__ float tile[64][68];
  in  += blockIdx.z * inSlab;
  out += blockIdx.z * outSlab;
  const int c0 = blockIdx.x * 64, r0 = blockIdx.y * 64;
  const int t = threadIdx.x;
  const int row = t >> 4, cq = t & 15;
  const float* src = in + (size_t)(r0 + row) * C + c0 + cq * 4;
#pragma unroll
  for (int p = 0; p < 4; ++p) {
    const float4 v = *(const float4*)(src + (size_t)(p * 16) * C);
    *(float4*)&tile[p * 16 + row][cq * 4] = v;
  }
  __syncthreads();
  const int oc = t >> 2, rq = t & 3;
  float vals[16];
#pragma unroll
  for (int i = 0; i < 16; ++i) vals[i] = tile[rq * 16 + i][oc];
  const int c = c0 + oc;
  int p;
  if (mode == 0) p = c;
  else p = ((c >> 4) << 5) + (c & 15) + (mode == 2 ? 16 : 0);
  bf16x8 o0, o1;
#pragma unroll
  for (int i = 0; i < 8; ++i) { o0[i] = (bf16)vals[i]; o1[i] = (bf16)vals[8 + i]; }
  bf16* dst = out + (size_t)p * R + r0 + rq * 16;
  *(bf16x8*)dst = o0;
  *(bf16x8*)(dst + 8) = o1;
}

// ---------------- GEMM1: gathered X rows x interleaved [Wg|Wu]^T, fused silu*up*wts -> H ----------------
// 1-D grid, XCD-aware decode: e = bid%8 pins each expert to one XCD (8 experts == 8 XCDs);
// mt varies fastest so consecutive same-XCD blocks share the same 512 KB B-panel (L2-hit),
// and the expert's gathered-A set (~4 MB) stays L2-resident.
__global__ __launch_bounds__(256, 4) void gemm_gateup(
    const bf16* __restrict__ X, const bf16* __restrict__ W, bf16* __restrict__ H,
    const int* __restrict__ cnt, const int* __restrict__ offs,
    const int* __restrict__ tok, const float* __restrict__ wts) {
  const int bid = blockIdx.x;
  const int e = bid & 7;
  const int s = bid >> 3;
  const int mt = s & 31;        // fastest: B-panel reuse within XCD
  const int nt = s >> 5;        // 0..21
  const int c = cnt[e];
  if (mt * 128 >= c) return;

  __shared__ bf16 sA[128 * 32];
  __shared__ bf16 sB[128 * 32];

  const int t = threadIdx.x, l = t & 63, w = t >> 6;
  const int iA0 = t, iA1 = t + 256;
  const int rA0 = iA0 >> 2, g0 = iA0 & 3;
  const int rA1 = iA1 >> 2, g1 = iA1 & 3;
  const int gr0 = tok[e * 4096 + (mt * 128 + rA0 < c ? mt * 128 + rA0 : c - 1)];
  const int gr1 = tok[e * 4096 + (mt * 128 + rA1 < c ? mt * 128 + rA1 : c - 1)];
  const bf16* pa0 = X + (size_t)gr0 * HIDDEN + g0 * 8;
  const bf16* pa1 = X + (size_t)gr1 * HIDDEN + g1 * 8;
  const bf16* pb0 = W + ((size_t)e * NGU + nt * 128 + rA0) * HIDDEN + g0 * 8;
  const bf16* pb1 = W + ((size_t)e * NGU + nt * 128 + rA1) * HIDDEN + g1 * 8;
  bf16* la0 = sA + iA0 * 8; bf16* la1 = sA + iA1 * 8;
  bf16* lb0 = sB + iA0 * 8; bf16* lb1 = sB + iA1 * 8;

  const int wm = (w >> 1) * 64, wn = (w & 1) * 64;
  const int r16 = l & 15, quad = l >> 4;
  const bf16* fA = sA + (wm + r16) * 32 + quad * 8;
  const bf16* fB = sB + (wn + r16) * 32 + quad * 8;

  f32x4 acc[4][4];
#pragma unroll
  for (int i = 0; i < 4; ++i)
#pragma unroll
    for (int j = 0; j < 4; ++j) acc[i][j] = (f32x4){0.f, 0.f, 0.f, 0.f};

  for (int kk = 0; kk < HIDDEN; kk += 32) {
    async16(pa0 + kk, la0); async16(pa1 + kk, la1);
    async16(pb0 + kk, lb0); async16(pb1 + kk, lb1);
    __syncthreads();
    bf16x8 a[4], b[4];
#pragma unroll
    for (int i = 0; i < 4; ++i) a[i] = *(const bf16x8*)(fA + i * 16 * 32);
#pragma unroll
    for (int j = 0; j < 4; ++j) b[j] = *(const bf16x8*)(fB + j * 16 * 32);
#pragma unroll
    for (int i = 0; i < 4; ++i)
#pragma unroll
      for (int j = 0; j < 4; ++j)
        acc[i][j] = __builtin_amdgcn_mfma_f32_16x16x32_bf16(a[i], b[j], acc[i][j], 0, 0, 0);
    __syncthreads();
  }

  // epilogue: columns interleaved g,u per 16 -> h = silu(g)*u*wts, 64 h-cols per block
  const int mLoc = mt * 128 + wm + quad * 4;
  const int hcol = nt * 64 + (wn >> 1) + r16;   // wn=0 -> +0, wn=64 -> +32
#pragma unroll
  for (int i = 0; i < 4; ++i)
#pragma unroll
    for (int r = 0; r < 4; ++r) {
      const int m = mLoc + i * 16 + r;
      const int mc = m < c ? m : c - 1;
      const float ws = wts[e * 4096 + mc];
      const float g0v = acc[i][0][r], u0v = acc[i][1][r];
      const float g1v = acc[i][2][r], u1v = acc[i][3][r];
      const float h0 = (g0v / (1.f + __expf(-g0v))) * u0v * ws;
      const float h1 = (g1v / (1.f + __expf(-g1v))) * u1v * ws;
      bf16* dst = H + (size_t)(offs[e] + m) * INTER + hcol;
      dst[0]  = (bf16)h0;
      dst[16] = (bf16)h1;
    }
}

// ---------------- GEMM2: H x Wdown^T, atomic scatter into out ----------------
// Same XCD-aware 1-D decode as GEMM1.
__global__ __launch_bounds__(256, 4) void gemm_down(
    const bf16* __restrict__ Hin, const bf16* __restrict__ W, float* __restrict__ out,
    const int* __restrict__ cnt, const int* __restrict__ offs,
    const int* __restrict__ tok) {
  const int bid = blockIdx.x;
  const int e = bid & 7;
  const int s = bid >> 3;
  const int mt = s & 31;        // fastest: B-panel reuse within XCD
  const int nt = s >> 5;        // 0..15
  const int c = cnt[e];
  if (mt * 128 >= c) return;

  __shared__ bf16 sA[128 * 32];
  __shared__ bf16 sB[128 * 32];

  const int t = threadIdx.x, l = t & 63, w = t >> 6;
  const int iA0 = t, iA1 = t + 256;
  const int rA0 = iA0 >> 2, g0 = iA0 & 3;
  const int rA1 = iA1 >> 2, g1 = iA1 & 3;
  const int base = offs[e] + mt * 128;
  const bf16* pa0 = Hin + (size_t)(base + rA0) * INTER + g0 * 8;
  const bf16* pa1 = Hin + (size_t)(base + rA1) * INTER + g1 * 8;
  const bf16* pb0 = W + ((size_t)e * HIDDEN + nt * 128 + rA0) * INTER + g0 * 8;
  const bf16* pb1 = W + ((size_t)e * HIDDEN + nt * 128 + rA1) * INTER + g1 * 8;
  bf16* la0 = sA + iA0 * 8; bf16* la1 = sA + iA1 * 8;
  bf16* lb0 = sB + iA0 * 8; bf16* lb1 = sB + iA1 * 8;

  const int wm = (w >> 1) * 64, wn = (w & 1) * 64;
  const int r16 = l & 15, quad = l >> 4;
  const bf16* fA = sA + (wm + r16) * 32 + quad * 8;
  const bf16* fB = sB + (wn + r16) * 32 + quad * 8;

  f32x4 acc[4][4];
#pragma unroll
  for (int i = 0; i < 4; ++i)
#pragma unroll
    for (int j = 0; j < 4; ++j) acc[i][j] = (f32x4){0.f, 0.f, 0.f, 0.f};

  for (int kk = 0; kk < INTER; kk += 32) {
    async16(pa0 + kk, la0); async16(pa1 + kk, la1);
    async16(pb0 + kk, lb0); async16(pb1 + kk, lb1);
    __syncthreads();
    bf16x8 a[4], b[4];
#pragma unroll
    for (int i = 0; i < 4; ++i) a[i] = *(const bf16x8*)(fA + i * 16 * 32);
#pragma unroll
    for (int j = 0; j < 4; ++j) b[j] = *(const bf16x8*)(fB + j * 16 * 32);
#pragma unroll
    for (int i = 0; i < 4; ++i)
#pragma unroll
      for (int j = 0; j < 4; ++j)
        acc[i][j] = __builtin_amdgcn_mfma_f32_16x16x32_bf16(a[i], b[j], acc[i][j], 0, 0, 0);
    __syncthreads();
  }

  const int mBase = mt * 128 + wm + quad * 4;
  const int colBase = nt * 128 + wn + r16;
#pragma unroll
  for (int i = 0; i < 4; ++i)
#pragma unroll
    for (int r = 0; r < 4; ++r) {
      const int m = mBase + i * 16 + r;
      if (m < c) {
        const int tkn = tok[e * 4096 + m];
        float* dst = out + (size_t)tkn * HIDDEN + colBase;
#pragma unroll
        for (int j = 0; j < 4; ++j) atomicAdd(dst + j * 16, acc[i][j][r]);
      }
    }
}

extern "C" void kernel_launch(void* const* d_in, const int* in_sizes, int n_in,
                              void* d_out, int out_size, void* d_ws, size_t ws_size,
                              hipStream_t stream) {
  const float* x  = (const float*)d_in[0];
  const float* rw = (const float*)d_in[1];
  const float* wg = (const float*)d_in[2];
  const float* wu = (const float*)d_in[3];
  const float* wd = (const float*)d_in[4];
  float* out = (float*)d_out;

  char* ws = (char*)d_ws;
  size_t o = 0;
  auto alloc = [&](size_t b) { void* p = ws + o; o += (b + 255) & ~(size_t)255; return p; };
  int*   cnt  = (int*)alloc(NE * 4);
  int*   offs = (int*)alloc((NE + 1) * 4);
  int*   tok  = (int*)alloc((size_t)NE * 4096 * 4);
  float* wts  = (float*)alloc((size_t)NE * 4096 * 4);
  bf16*  xb   = (bf16*)alloc((size_t)TOKENS * HIDDEN * 2);
  bf16*  wgu  = (bf16*)alloc((size_t)NE * NGU * HIDDEN * 2);
  bf16*  wdt  = (bf16*)alloc((size_t)NE * HIDDEN * INTER * 2);
  bf16*  h    = (bf16*)alloc((size_t)CAP_ROWS * INTER * 2);

  hipMemsetAsync(cnt, 0, NE * 4, stream);
  hipMemsetAsync(d_out, 0, (size_t)TOKENS * HIDDEN * 4, stream);

  router_kernel<<<TOKENS / 4, 256, 0, stream>>>(x, rw, xb, cnt, tok, wts);
  scan_kernel<<<1, 64, 0, stream>>>(cnt, offs);

  // w_gate [E][H][I] -> interleaved rows of wgu [E][2816][H]
  transpose64<<<dim3(INTER / 64, HIDDEN / 64, NE), 256, 0, stream>>>(
      wg, wgu, HIDDEN, INTER, (size_t)HIDDEN * INTER, (size_t)NGU * HIDDEN, 1);
  transpose64<<<dim3(INTER / 64, HIDDEN / 64, NE), 256, 0, stream>>>(
      wu, wgu, HIDDEN, INTER, (size_t)HIDDEN * INTER, (size_t)NGU * HIDDEN, 2);
  // w_down [E][I][H] -> wdt [E][H][I]
  transpose64<<<dim3(HIDDEN / 64, INTER / 64, NE), 256, 0, stream>>>(
      wd, wdt, INTER, HIDDEN, (size_t)INTER * HIDDEN, (size_t)HIDDEN * INTER, 0);

  gemm_gateup<<<dim3(NE * (TOKENS / 128) * (NGU / 128)), 256, 0, stream>>>(
      xb, wgu, h, cnt, offs, tok, wts);
  gemm_down<<<dim3(NE * (TOKENS / 128) * (HIDDEN / 128)), 256, 0, stream>>>(
      h, wdt, out, cnt, offs, tok);
}

// Round 2
// 692.727 us; speedup vs baseline: 1.0073x; 1.0026x over previous
//
#include <hip/hip_runtime.h>
#include <hip/hip_bf16.h>
#include <cstdint>
#include <cstddef>

#define TOKENS 4096
#define HIDDEN 2048
#define INTER  1408
#define NE     8
#define NGU    2816            // 2*INTER (gate | up, 16-col interleaved)
#define CAP_ROWS 9216          // >= 8192 assignments + 8*127 tile pad

typedef __bf16 bf16;
typedef __bf16 bf16x8 __attribute__((ext_vector_type(8)));
typedef float  f32x4  __attribute__((ext_vector_type(4)));

__device__ __forceinline__ void async16(const void* g, void* l) {
  __builtin_amdgcn_global_load_lds((const __attribute__((address_space(1))) void*)g,
                                   (__attribute__((address_space(3))) void*)l,
                                   16, 0, 0);
}

// ---------------- router: logits, top-2, renorm weights; also x -> bf16 ----------------
// Also records the inverse map inv[t*2+k] = (e<<12)|pos for the combine kernel.
__global__ void router_kernel(const float* __restrict__ x, const float* __restrict__ rw,
                              bf16* __restrict__ xb, int* __restrict__ cnt,
                              int* __restrict__ tok, float* __restrict__ wts,
                              int* __restrict__ inv) {
  const int w = threadIdx.x >> 6, l = threadIdx.x & 63;
  const int t = blockIdx.x * 4 + w;
  const float4* x4 = (const float4*)(x + (size_t)t * HIDDEN);
  const float4* r4 = (const float4*)rw;
  float acc[NE];
#pragma unroll
  for (int e = 0; e < NE; ++e) acc[e] = 0.f;
#pragma unroll
  for (int c = 0; c < 8; ++c) {
    const int idx = c * 64 + l;
    const float4 v = x4[idx];
    bf16* dst = xb + (size_t)t * HIDDEN + idx * 4;
    dst[0] = (bf16)v.x; dst[1] = (bf16)v.y; dst[2] = (bf16)v.z; dst[3] = (bf16)v.w;
#pragma unroll
    for (int e = 0; e < NE; ++e) {
      const float4 u = r4[e * 512 + idx];
      acc[e] += v.x * u.x + v.y * u.y + v.z * u.z + v.w * u.w;
    }
  }
#pragma unroll
  for (int e = 0; e < NE; ++e)
#pragma unroll
    for (int s = 32; s > 0; s >>= 1) acc[e] += __shfl_xor(acc[e], s, 64);
  if (l == 0) {
    int i0 = 0; float l0 = acc[0];
#pragma unroll
    for (int e = 1; e < NE; ++e) if (acc[e] > l0) { l0 = acc[e]; i0 = e; }
    int i1 = -1; float l1 = -3.4e38f;
#pragma unroll
    for (int e = 0; e < NE; ++e) if (e != i0 && acc[e] > l1) { l1 = acc[e]; i1 = e; }
    // renormalized top-2 softmax == softmax over the two top logits
    const float w0 = 1.f / (1.f + __expf(l1 - l0));
    const float w1 = 1.f - w0;
    int p = atomicAdd(&cnt[i0], 1);
    tok[i0 * 4096 + p] = t; wts[i0 * 4096 + p] = w0; inv[t * 2]     = (i0 << 12) | p;
    p = atomicAdd(&cnt[i1], 1);
    tok[i1 * 4096 + p] = t; wts[i1 * 4096 + p] = w1; inv[t * 2 + 1] = (i1 << 12) | p;
  }
}

// ---------------- 128-aligned exclusive scan of expert counts (8 entries) ----------------
__global__ void scan_kernel(const int* __restrict__ cnt, int* __restrict__ offs) {
  if (threadIdx.x == 0 && blockIdx.x == 0) {
    int o = 0;
    for (int e = 0; e < NE; ++e) { offs[e] = o; o += ((cnt[e] + 127) >> 7) << 7; }
    offs[NE] = o;
  }
}

// ---------------- 64x64 tiled transpose + fp32->bf16 ----------------
// in[R][C] fp32 -> out[p(c)][R] bf16.  mode 0: p=c (w_down)
// mode 1: gate -> p = (c/16)*32 + c%16 ; mode 2: up -> p = (c/16)*32 + 16 + c%16
__global__ __launch_bounds__(256) void transpose64(
    const float* __restrict__ in, bf16* __restrict__ out, int R, int C,
    size_t inSlab, size_t outSlab, int mode) {
  __shared__ float tile[64][68];
  in  += blockIdx.z * inSlab;
  out += blockIdx.z * outSlab;
  const int c0 = blockIdx.x * 64, r0 = blockIdx.y * 64;
  const int t = threadIdx.x;
  const int row = t >> 4, cq = t & 15;
  const float* src = in + (size_t)(r0 + row) * C + c0 + cq * 4;
#pragma unroll
  for (int p = 0; p < 4; ++p) {
    const float4 v = *(const float4*)(src + (size_t)(p * 16) * C);
    *(float4*)&tile[p * 16 + row][cq * 4] = v;
  }
  __syncthreads();
  const int oc = t >> 2, rq = t & 3;
  float vals[16];
#pragma unroll
  for (int i = 0; i < 16; ++i) vals[i] = tile[rq * 16 + i][oc];
  const int c = c0 + oc;
  int p;
  if (mode == 0) p = c;
  else p = ((c >> 4) << 5) + (c & 15) + (mode == 2 ? 16 : 0);
  bf16x8 o0, o1;
#pragma unroll
  for (int i = 0; i < 8; ++i) { o0[i] = (bf16)vals[i]; o1[i] = (bf16)vals[8 + i]; }
  bf16* dst = out + (size_t)p * R + r0 + rq * 16;
  *(bf16x8*)dst = o0;
  *(bf16x8*)(dst + 8) = o1;
}

// ---------------- GEMM1: gathered X rows x interleaved [Wg|Wu]^T, fused silu*up*wts -> H ----------------
// 1-D grid, XCD-aware decode: e = bid%8 pins each expert to one XCD (8 experts == 8 XCDs).
// 2-phase double-buffered K-loop (T3-min): stage tile k+1 while computing tile k; one barrier/step.
__global__ __launch_bounds__(256, 4) void gemm_gateup(
    const bf16* __restrict__ X, const bf16* __restrict__ W, bf16* __restrict__ H,
    const int* __restrict__ cnt, const int* __restrict__ offs,
    const int* __restrict__ tok, const float* __restrict__ wts) {
  const int bid = blockIdx.x;
  const int e = bid & 7;
  const int s = bid >> 3;
  const int mt = s & 31;        // fastest: B-panel reuse within XCD
  const int nt = s >> 5;        // 0..21
  const int c = cnt[e];
  if (mt * 128 >= c) return;

  __shared__ bf16 sA[2][128 * 32];
  __shared__ bf16 sB[2][128 * 32];

  const int t = threadIdx.x, l = t & 63, w = t >> 6;
  const int iA0 = t, iA1 = t + 256;
  const int rA0 = iA0 >> 2, g0 = iA0 & 3;
  const int rA1 = iA1 >> 2, g1 = iA1 & 3;
  const int gr0 = tok[e * 4096 + (mt * 128 + rA0 < c ? mt * 128 + rA0 : c - 1)];
  const int gr1 = tok[e * 4096 + (mt * 128 + rA1 < c ? mt * 128 + rA1 : c - 1)];
  const bf16* pa0 = X + (size_t)gr0 * HIDDEN + g0 * 8;
  const bf16* pa1 = X + (size_t)gr1 * HIDDEN + g1 * 8;
  const bf16* pb0 = W + ((size_t)e * NGU + nt * 128 + rA0) * HIDDEN + g0 * 8;
  const bf16* pb1 = W + ((size_t)e * NGU + nt * 128 + rA1) * HIDDEN + g1 * 8;
  bf16* la0 = sA[0] + iA0 * 8; bf16* la1 = sA[0] + iA1 * 8;
  bf16* lb0 = sB[0] + iA0 * 8; bf16* lb1 = sB[0] + iA1 * 8;

  const int wm = (w >> 1) * 64, wn = (w & 1) * 64;
  const int r16 = l & 15, quad = l >> 4;
  const bf16* fA = sA[0] + (wm + r16) * 32 + quad * 8;
  const bf16* fB = sB[0] + (wn + r16) * 32 + quad * 8;

  f32x4 acc[4][4];
#pragma unroll
  for (int i = 0; i < 4; ++i)
#pragma unroll
    for (int j = 0; j < 4; ++j) acc[i][j] = (f32x4){0.f, 0.f, 0.f, 0.f};

  // prologue: stage tile 0 into buffer 0
  async16(pa0, la0); async16(pa1, la1);
  async16(pb0, lb0); async16(pb1, lb1);
  __syncthreads();
  int cur = 0;
  for (int kk = 32; kk < HIDDEN; kk += 32) {
    const int so = (cur ^ 1) * 4096;       // stage into other buffer
    async16(pa0 + kk, la0 + so); async16(pa1 + kk, la1 + so);
    async16(pb0 + kk, lb0 + so); async16(pb1 + kk, lb1 + so);
    const int co = cur * 4096;             // compute current buffer
    bf16x8 a[4], b[4];
#pragma unroll
    for (int i = 0; i < 4; ++i) a[i] = *(const bf16x8*)(fA + co + i * 16 * 32);
#pragma unroll
    for (int j = 0; j < 4; ++j) b[j] = *(const bf16x8*)(fB + co + j * 16 * 32);
#pragma unroll
    for (int i = 0; i < 4; ++i)
#pragma unroll
      for (int j = 0; j < 4; ++j)
        acc[i][j] = __builtin_amdgcn_mfma_f32_16x16x32_bf16(a[i], b[j], acc[i][j], 0, 0, 0);
    __syncthreads();                       // drains vmcnt (staged tile ready) in one barrier
    cur ^= 1;
  }
  {
    const int co = cur * 4096;             // epilogue tile (no prefetch)
    bf16x8 a[4], b[4];
#pragma unroll
    for (int i = 0; i < 4; ++i) a[i] = *(const bf16x8*)(fA + co + i * 16 * 32);
#pragma unroll
    for (int j = 0; j < 4; ++j) b[j] = *(const bf16x8*)(fB + co + j * 16 * 32);
#pragma unroll
    for (int i = 0; i < 4; ++i)
#pragma unroll
      for (int j = 0; j < 4; ++j)
        acc[i][j] = __builtin_amdgcn_mfma_f32_16x16x32_bf16(a[i], b[j], acc[i][j], 0, 0, 0);
  }

  // epilogue: columns interleaved g,u per 16 -> h = silu(g)*u*wts, 64 h-cols per block
  const int mLoc = mt * 128 + wm + quad * 4;
  const int hcol = nt * 64 + (wn >> 1) + r16;   // wn=0 -> +0, wn=64 -> +32
#pragma unroll
  for (int i = 0; i < 4; ++i)
#pragma unroll
    for (int r = 0; r < 4; ++r) {
      const int m = mLoc + i * 16 + r;
      const int mc = m < c ? m : c - 1;
      const float ws = wts[e * 4096 + mc];
      const float g0v = acc[i][0][r], u0v = acc[i][1][r];
      const float g1v = acc[i][2][r], u1v = acc[i][3][r];
      const float h0 = (g0v / (1.f + __expf(-g0v))) * u0v * ws;
      const float h1 = (g1v / (1.f + __expf(-g1v))) * u1v * ws;
      bf16* dst = H + (size_t)(offs[e] + m) * INTER + hcol;
      dst[0]  = (bf16)h0;
      dst[16] = (bf16)h1;
    }
}

// ---------------- GEMM2: H x Wdown^T -> per-assignment rows in ybuf (NO atomics) ----------------
// Same XCD-aware 1-D decode and 2-phase double-buffer as GEMM1.
__global__ __launch_bounds__(256, 4) void gemm_down(
    const bf16* __restrict__ Hin, const bf16* __restrict__ W, float* __restrict__ ybuf,
    const int* __restrict__ cnt, const int* __restrict__ offs) {
  const int bid = blockIdx.x;
  const int e = bid & 7;
  const int s = bid >> 3;
  const int mt = s & 31;        // fastest: B-panel reuse within XCD
  const int nt = s >> 5;        // 0..15
  const int c = cnt[e];
  if (mt * 128 >= c) return;

  __shared__ bf16 sA[2][128 * 32];
  __shared__ bf16 sB[2][128 * 32];

  const int t = threadIdx.x, l = t & 63, w = t >> 6;
  const int iA0 = t, iA1 = t + 256;
  const int rA0 = iA0 >> 2, g0 = iA0 & 3;
  const int rA1 = iA1 >> 2, g1 = iA1 & 3;
  const int base = offs[e] + mt * 128;
  const bf16* pa0 = Hin + (size_t)(base + rA0) * INTER + g0 * 8;
  const bf16* pa1 = Hin + (size_t)(base + rA1) * INTER + g1 * 8;
  const bf16* pb0 = W + ((size_t)e * HIDDEN + nt * 128 + rA0) * INTER + g0 * 8;
  const bf16* pb1 = W + ((size_t)e * HIDDEN + nt * 128 + rA1) * INTER + g1 * 8;
  bf16* la0 = sA[0] + iA0 * 8; bf16* la1 = sA[0] + iA1 * 8;
  bf16* lb0 = sB[0] + iA0 * 8; bf16* lb1 = sB[0] + iA1 * 8;

  const int wm = (w >> 1) * 64, wn = (w & 1) * 64;
  const int r16 = l & 15, quad = l >> 4;
  const bf16* fA = sA[0] + (wm + r16) * 32 + quad * 8;
  const bf16* fB = sB[0] + (wn + r16) * 32 + quad * 8;

  f32x4 acc[4][4];
#pragma unroll
  for (int i = 0; i < 4; ++i)
#pragma unroll
    for (int j = 0; j < 4; ++j) acc[i][j] = (f32x4){0.f, 0.f, 0.f, 0.f};

  // prologue: stage tile 0 into buffer 0
  async16(pa0, la0); async16(pa1, la1);
  async16(pb0, lb0); async16(pb1, lb1);
  __syncthreads();
  int cur = 0;
  for (int kk = 32; kk < INTER; kk += 32) {
    const int so = (cur ^ 1) * 4096;
    async16(pa0 + kk, la0 + so); async16(pa1 + kk, la1 + so);
    async16(pb0 + kk, lb0 + so); async16(pb1 + kk, lb1 + so);
    const int co = cur * 4096;
    bf16x8 a[4], b[4];
#pragma unroll
    for (int i = 0; i < 4; ++i) a[i] = *(const bf16x8*)(fA + co + i * 16 * 32);
#pragma unroll
    for (int j = 0; j < 4; ++j) b[j] = *(const bf16x8*)(fB + co + j * 16 * 32);
#pragma unroll
    for (int i = 0; i < 4; ++i)
#pragma unroll
      for (int j = 0; j < 4; ++j)
        acc[i][j] = __builtin_amdgcn_mfma_f32_16x16x32_bf16(a[i], b[j], acc[i][j], 0, 0, 0);
    __syncthreads();
    cur ^= 1;
  }
  {
    const int co = cur * 4096;
    bf16x8 a[4], b[4];
#pragma unroll
    for (int i = 0; i < 4; ++i) a[i] = *(const bf16x8*)(fA + co + i * 16 * 32);
#pragma unroll
    for (int j = 0; j < 4; ++j) b[j] = *(const bf16x8*)(fB + co + j * 16 * 32);
#pragma unroll
    for (int i = 0; i < 4; ++i)
#pragma unroll
      for (int j = 0; j < 4; ++j)
        acc[i][j] = __builtin_amdgcn_mfma_f32_16x16x32_bf16(a[i], b[j], acc[i][j], 0, 0, 0);
  }

  const int mBase = mt * 128 + wm + quad * 4;
  const int colBase = nt * 128 + wn + r16;
#pragma unroll
  for (int i = 0; i < 4; ++i)
#pragma unroll
    for (int r = 0; r < 4; ++r) {
      const int m = mBase + i * 16 + r;
      if (m < c) {
        float* dst = ybuf + (size_t)(offs[e] + m) * HIDDEN + colBase;
#pragma unroll
        for (int j = 0; j < 4; ++j) dst[j * 16] = acc[i][j][r];
      }
    }
}

// ---------------- combine: out[t] = y[slot0(t)] + y[slot1(t)] ----------------
__global__ __launch_bounds__(256) void combine_kernel(
    const float* __restrict__ y, const int* __restrict__ inv,
    const int* __restrict__ offs, float* __restrict__ out) {
  const int idx = blockIdx.x * 256 + threadIdx.x;   // over TOKENS*512 float4s
  const int tkn = idx >> 9, q = idx & 511;
  const int v0 = inv[tkn * 2], v1 = inv[tkn * 2 + 1];
  const size_t r0 = (size_t)(offs[v0 >> 12] + (v0 & 4095));
  const size_t r1 = (size_t)(offs[v1 >> 12] + (v1 & 4095));
  const float4 a = ((const float4*)y)[r0 * 512 + q];
  const float4 b = ((const float4*)y)[r1 * 512 + q];
  float4 o; o.x = a.x + b.x; o.y = a.y + b.y; o.z = a.z + b.z; o.w = a.w + b.w;
  ((float4*)out)[idx] = o;
}

extern "C" void kernel_launch(void* const* d_in, const int* in_sizes, int n_in,
                              void* d_out, int out_size, void* d_ws, size_t ws_size,
                              hipStream_t stream) {
  const float* x  = (const float*)d_in[0];
  const float* rw = (const float*)d_in[1];
  const float* wg = (const float*)d_in[2];
  const float* wu = (const float*)d_in[3];
  const float* wd = (const float*)d_in[4];
  float* out = (float*)d_out;

  char* ws = (char*)d_ws;
  size_t o = 0;
  auto alloc = [&](size_t b) { void* p = ws + o; o += (b + 255) & ~(size_t)255; return p; };
  int*   cnt  = (int*)alloc(NE * 4);
  int*   offs = (int*)alloc((NE + 1) * 4);
  int*   tok  = (int*)alloc((size_t)NE * 4096 * 4);
  float* wts  = (float*)alloc((size_t)NE * 4096 * 4);
  int*   inv  = (int*)alloc((size_t)TOKENS * 2 * 4);
  bf16*  xb   = (bf16*)alloc((size_t)TOKENS * HIDDEN * 2);
  bf16*  wgu  = (bf16*)alloc((size_t)NE * NGU * HIDDEN * 2);
  bf16*  wdt  = (bf16*)alloc((size_t)NE * HIDDEN * INTER * 2);
  bf16*  h    = (bf16*)alloc((size_t)CAP_ROWS * INTER * 2);
  // ybuf (75.5 MB) aliases wgu (92.3 MB): wgu is dead once gemm_gateup completes,
  // and gemm_down (which writes ybuf) is stream-ordered after it.
  float* ybuf = (float*)wgu;

  hipMemsetAsync(cnt, 0, NE * 4, stream);

  router_kernel<<<TOKENS / 4, 256, 0, stream>>>(x, rw, xb, cnt, tok, wts, inv);
  scan_kernel<<<1, 64, 0, stream>>>(cnt, offs);

  // w_gate [E][H][I] -> interleaved rows of wgu [E][2816][H]
  transpose64<<<dim3(INTER / 64, HIDDEN / 64, NE), 256, 0, stream>>>(
      wg, wgu, HIDDEN, INTER, (size_t)HIDDEN * INTER, (size_t)NGU * HIDDEN, 1);
  transpose64<<<dim3(INTER / 64, HIDDEN / 64, NE), 256, 0, stream>>>(
      wu, wgu, HIDDEN, INTER, (size_t)HIDDEN * INTER, (size_t)NGU * HIDDEN, 2);
  // w_down [E][I][H] -> wdt [E][H][I]
  transpose64<<<dim3(HIDDEN / 64, INTER / 64, NE), 256, 0, stream>>>(
      wd, wdt, INTER, HIDDEN, (size_t)INTER * HIDDEN, (size_t)HIDDEN * INTER, 0);

  gemm_gateup<<<dim3(NE * (TOKENS / 128) * (NGU / 128)), 256, 0, stream>>>(
      xb, wgu, h, cnt, offs, tok, wts);
  gemm_down<<<dim3(NE * (TOKENS / 128) * (HIDDEN / 128)), 256, 0, stream>>>(
      h, wdt, ybuf, cnt, offs);
  combine_kernel<<<dim3(TOKENS * (HIDDEN / 4) / 256), 256, 0, stream>>>(
      ybuf, inv, offs, out);
}

// Round 3
// 678.478 us; speedup vs baseline: 1.0285x; 1.0210x over previous
//
#include <hip/hip_runtime.h>
#include <hip/hip_bf16.h>
#include <cstdint>
#include <cstddef>

#define TOKENS 4096
#define HIDDEN 2048
#define INTER  1408
#define NE     8
#define NGU    2816            // 2*INTER (gate | up, 16-col interleaved)
#define CAP_ROWS 9216          // >= 8192 assignments + 8*127 tile pad

typedef __bf16 bf16;
typedef __bf16 bf16x8 __attribute__((ext_vector_type(8)));
typedef __bf16 bf16x4 __attribute__((ext_vector_type(4)));
typedef float  f32x4  __attribute__((ext_vector_type(4)));

__device__ __forceinline__ void async16(const void* g, void* l) {
  __builtin_amdgcn_global_load_lds((const __attribute__((address_space(1))) void*)g,
                                   (__attribute__((address_space(3))) void*)l,
                                   16, 0, 0);
}

// ---------------- router: logits, top-2, renorm weights; also x -> bf16 ----------------
__global__ void router_kernel(const float* __restrict__ x, const float* __restrict__ rw,
                              bf16* __restrict__ xb, int* __restrict__ cnt,
                              int* __restrict__ tok, float* __restrict__ wts,
                              int* __restrict__ inv) {
  const int w = threadIdx.x >> 6, l = threadIdx.x & 63;
  const int t = blockIdx.x * 4 + w;
  const float4* x4 = (const float4*)(x + (size_t)t * HIDDEN);
  const float4* r4 = (const float4*)rw;
  float acc[NE];
#pragma unroll
  for (int e = 0; e < NE; ++e) acc[e] = 0.f;
#pragma unroll
  for (int c = 0; c < 8; ++c) {
    const int idx = c * 64 + l;
    const float4 v = x4[idx];
    bf16* dst = xb + (size_t)t * HIDDEN + idx * 4;
    dst[0] = (bf16)v.x; dst[1] = (bf16)v.y; dst[2] = (bf16)v.z; dst[3] = (bf16)v.w;
#pragma unroll
    for (int e = 0; e < NE; ++e) {
      const float4 u = r4[e * 512 + idx];
      acc[e] += v.x * u.x + v.y * u.y + v.z * u.z + v.w * u.w;
    }
  }
#pragma unroll
  for (int e = 0; e < NE; ++e)
#pragma unroll
    for (int s = 32; s > 0; s >>= 1) acc[e] += __shfl_xor(acc[e], s, 64);
  if (l == 0) {
    int i0 = 0; float l0 = acc[0];
#pragma unroll
    for (int e = 1; e < NE; ++e) if (acc[e] > l0) { l0 = acc[e]; i0 = e; }
    int i1 = -1; float l1 = -3.4e38f;
#pragma unroll
    for (int e = 0; e < NE; ++e) if (e != i0 && acc[e] > l1) { l1 = acc[e]; i1 = e; }
    const float w0 = 1.f / (1.f + __expf(l1 - l0));
    const float w1 = 1.f - w0;
    int p = atomicAdd(&cnt[i0], 1);
    tok[i0 * 4096 + p] = t; wts[i0 * 4096 + p] = w0; inv[t * 2]     = (i0 << 12) | p;
    p = atomicAdd(&cnt[i1], 1);
    tok[i1 * 4096 + p] = t; wts[i1 * 4096 + p] = w1; inv[t * 2 + 1] = (i1 << 12) | p;
  }
}

// ---------------- 128-aligned exclusive scan of expert counts (8 entries) ----------------
__global__ void scan_kernel(const int* __restrict__ cnt, int* __restrict__ offs) {
  if (threadIdx.x == 0 && blockIdx.x == 0) {
    int o = 0;
    for (int e = 0; e < NE; ++e) { offs[e] = o; o += ((cnt[e] + 127) >> 7) << 7; }
    offs[NE] = o;
  }
}

// ---------------- fused weight prep: 3 transposes in one launch ----------------
// which 0: wg (mode1), 1: wu (mode2), 2: wd (mode0). 64x64 fp32 tile -> bf16 transposed.
// LDS pad 65 (68%32==4 caused 4-way column-read conflicts; 65 -> free).
__global__ __launch_bounds__(256) void prep_weights(
    const float* __restrict__ wg, const float* __restrict__ wu, const float* __restrict__ wd,
    bf16* __restrict__ wgu, bf16* __restrict__ wdt) {
  __shared__ float tile[64][65];
  const int bid = blockIdx.x;
  const int which = bid / 5632;
  const int rem = bid - which * 5632;
  const int e = rem & 7;
  const int tid2 = rem >> 3;          // 0..703
  const float* in; bf16* out; int R, C, c0, r0, mode;
  if (which == 2) {
    in = wd + (size_t)e * INTER * HIDDEN; out = wdt + (size_t)e * HIDDEN * INTER;
    R = INTER; C = HIDDEN; c0 = (tid2 & 31) * 64; r0 = (tid2 >> 5) * 64; mode = 0;
  } else {
    in = (which ? wu : wg) + (size_t)e * HIDDEN * INTER; out = wgu + (size_t)e * NGU * HIDDEN;
    R = HIDDEN; C = INTER; c0 = (tid2 % 22) * 64; r0 = (tid2 / 22) * 64; mode = which + 1;
  }
  const int t = threadIdx.x;
  const int row = t >> 4, cq = t & 15;
  const float* src = in + (size_t)(r0 + row) * C + c0 + cq * 4;
#pragma unroll
  for (int p = 0; p < 4; ++p) {
    const float4 v = *(const float4*)(src + (size_t)(p * 16) * C);
    *(float4*)&tile[p * 16 + row][cq * 4] = v;
  }
  __syncthreads();
  const int oc = t >> 2, rq = t & 3;
  float vals[16];
#pragma unroll
  for (int i = 0; i < 16; ++i) vals[i] = tile[rq * 16 + i][oc];
  const int c = c0 + oc;
  int p;
  if (mode == 0) p = c;
  else p = ((c >> 4) << 5) + (c & 15) + (mode == 2 ? 16 : 0);
  bf16x8 o0, o1;
#pragma unroll
  for (int i = 0; i < 8; ++i) { o0[i] = (bf16)vals[i]; o1[i] = (bf16)vals[8 + i]; }
  bf16* dst = out + (size_t)p * R + r0 + rq * 16;
  *(bf16x8*)dst = o0;
  *(bf16x8*)(dst + 8) = o1;
}

// ---------------- GEMM1: gathered X rows x interleaved [Wg|Wu]^T, fused silu*up*wts -> H ----------------
// XCD-pinned 1-D grid (e = bid&7). 1-phase K-loop (2ph dbuf measured -16us, reverted).
// SWAPPED mfma operands: mfma(b, a) puts N on the D-row dim -> each lane's 4 acc regs are
// consecutive N columns -> vectorized epilogue stores (8B for H, 16B for ybuf).
__global__ __launch_bounds__(256, 4) void gemm_gateup(
    const bf16* __restrict__ X, const bf16* __restrict__ W, bf16* __restrict__ H,
    const int* __restrict__ cnt, const int* __restrict__ offs,
    const int* __restrict__ tok, const float* __restrict__ wts) {
  const int bid = blockIdx.x;
  const int e = bid & 7;
  const int s = bid >> 3;
  const int mt = s & 31;
  const int nt = s >> 5;
  const int c = cnt[e];
  if (mt * 128 >= c) return;

  __shared__ bf16 sA[128 * 32];
  __shared__ bf16 sB[128 * 32];

  const int t = threadIdx.x, l = t & 63, w = t >> 6;
  const int iA0 = t, iA1 = t + 256;
  const int rA0 = iA0 >> 2, g0 = iA0 & 3;
  const int rA1 = iA1 >> 2, g1 = iA1 & 3;
  const int gr0 = tok[e * 4096 + (mt * 128 + rA0 < c ? mt * 128 + rA0 : c - 1)];
  const int gr1 = tok[e * 4096 + (mt * 128 + rA1 < c ? mt * 128 + rA1 : c - 1)];
  const bf16* pa0 = X + (size_t)gr0 * HIDDEN + g0 * 8;
  const bf16* pa1 = X + (size_t)gr1 * HIDDEN + g1 * 8;
  const bf16* pb0 = W + ((size_t)e * NGU + nt * 128 + rA0) * HIDDEN + g0 * 8;
  const bf16* pb1 = W + ((size_t)e * NGU + nt * 128 + rA1) * HIDDEN + g1 * 8;
  bf16* la0 = sA + iA0 * 8; bf16* la1 = sA + iA1 * 8;
  bf16* lb0 = sB + iA0 * 8; bf16* lb1 = sB + iA1 * 8;

  const int wm = (w >> 1) * 64, wn = (w & 1) * 64;
  const int r16 = l & 15, quad = l >> 4;
  const bf16* fA = sA + (wm + r16) * 32 + quad * 8;
  const bf16* fB = sB + (wn + r16) * 32 + quad * 8;

  f32x4 acc[4][4];
#pragma unroll
  for (int i = 0; i < 4; ++i)
#pragma unroll
    for (int j = 0; j < 4; ++j) acc[i][j] = (f32x4){0.f, 0.f, 0.f, 0.f};

  for (int kk = 0; kk < HIDDEN; kk += 32) {
    async16(pa0 + kk, la0); async16(pa1 + kk, la1);
    async16(pb0 + kk, lb0); async16(pb1 + kk, lb1);
    __syncthreads();
    bf16x8 a[4], b[4];
#pragma unroll
    for (int i = 0; i < 4; ++i) a[i] = *(const bf16x8*)(fA + i * 16 * 32);
#pragma unroll
    for (int j = 0; j < 4; ++j) b[j] = *(const bf16x8*)(fB + j * 16 * 32);
#pragma unroll
    for (int i = 0; i < 4; ++i)
#pragma unroll
      for (int j = 0; j < 4; ++j)
        acc[i][j] = __builtin_amdgcn_mfma_f32_16x16x32_bf16(b[j], a[i], acc[i][j], 0, 0, 0);
    __syncthreads();
  }

  // swapped layout: lane holds n = wn + j*16 + quad*4 + r (r=reg), m = wm + i*16 + r16
  // gu-interleave: j even = gate 16-group, j odd = up 16-group; hcol = (p>>5)*16 + (p&15)
  const int mRowBase = mt * 128 + wm + r16;
  const int hcolBase = nt * 64 + (wn >> 1) + quad * 4;
#pragma unroll
  for (int i = 0; i < 4; ++i) {
    const int m = mRowBase + i * 16;
    const int mc = m < c ? m : c - 1;
    const float ws = wts[e * 4096 + mc];
    bf16* rowp = H + (size_t)(offs[e] + m) * INTER;
#pragma unroll
    for (int jp = 0; jp < 2; ++jp) {
      bf16x4 hv;
#pragma unroll
      for (int r = 0; r < 4; ++r) {
        const float g = acc[i][2 * jp][r];
        const float u = acc[i][2 * jp + 1][r];
        hv[r] = (bf16)((g / (1.f + __expf(-g))) * u * ws);
      }
      *(bf16x4*)(rowp + hcolBase + jp * 16) = hv;
    }
  }
}

// ---------------- GEMM2: H x Wdown^T -> per-assignment rows in ybuf (no atomics) ----------------
__global__ __launch_bounds__(256, 4) void gemm_down(
    const bf16* __restrict__ Hin, const bf16* __restrict__ W, float* __restrict__ ybuf,
    const int* __restrict__ cnt, const int* __restrict__ offs) {
  const int bid = blockIdx.x;
  const int e = bid & 7;
  const int s = bid >> 3;
  const int mt = s & 31;
  const int nt = s >> 5;
  const int c = cnt[e];
  if (mt * 128 >= c) return;

  __shared__ bf16 sA[128 * 32];
  __shared__ bf16 sB[128 * 32];

  const int t = threadIdx.x, l = t & 63, w = t >> 6;
  const int iA0 = t, iA1 = t + 256;
  const int rA0 = iA0 >> 2, g0 = iA0 & 3;
  const int rA1 = iA1 >> 2, g1 = iA1 & 3;
  const int base = offs[e] + mt * 128;
  const bf16* pa0 = Hin + (size_t)(base + rA0) * INTER + g0 * 8;
  const bf16* pa1 = Hin + (size_t)(base + rA1) * INTER + g1 * 8;
  const bf16* pb0 = W + ((size_t)e * HIDDEN + nt * 128 + rA0) * INTER + g0 * 8;
  const bf16* pb1 = W + ((size_t)e * HIDDEN + nt * 128 + rA1) * INTER + g1 * 8;
  bf16* la0 = sA + iA0 * 8; bf16* la1 = sA + iA1 * 8;
  bf16* lb0 = sB + iA0 * 8; bf16* lb1 = sB + iA1 * 8;

  const int wm = (w >> 1) * 64, wn = (w & 1) * 64;
  const int r16 = l & 15, quad = l >> 4;
  const bf16* fA = sA + (wm + r16) * 32 + quad * 8;
  const bf16* fB = sB + (wn + r16) * 32 + quad * 8;

  f32x4 acc[4][4];
#pragma unroll
  for (int i = 0; i < 4; ++i)
#pragma unroll
    for (int j = 0; j < 4; ++j) acc[i][j] = (f32x4){0.f, 0.f, 0.f, 0.f};

  for (int kk = 0; kk < INTER; kk += 32) {
    async16(pa0 + kk, la0); async16(pa1 + kk, la1);
    async16(pb0 + kk, lb0); async16(pb1 + kk, lb1);
    __syncthreads();
    bf16x8 a[4], b[4];
#pragma unroll
    for (int i = 0; i < 4; ++i) a[i] = *(const bf16x8*)(fA + i * 16 * 32);
#pragma unroll
    for (int j = 0; j < 4; ++j) b[j] = *(const bf16x8*)(fB + j * 16 * 32);
#pragma unroll
    for (int i = 0; i < 4; ++i)
#pragma unroll
      for (int j = 0; j < 4; ++j)
        acc[i][j] = __builtin_amdgcn_mfma_f32_16x16x32_bf16(b[j], a[i], acc[i][j], 0, 0, 0);
    __syncthreads();
  }

  // swapped layout: n = wn + j*16 + quad*4 + r (acc regs = consecutive n) -> float4 stores
  const int mRowBase = mt * 128 + wm + r16;
  const int colBase = nt * 128 + wn + quad * 4;
#pragma unroll
  for (int i = 0; i < 4; ++i) {
    const int m = mRowBase + i * 16;
    if (m < c) {
      float* rowp = ybuf + (size_t)(offs[e] + m) * HIDDEN + colBase;
#pragma unroll
      for (int j = 0; j < 4; ++j)
        *(f32x4*)(rowp + j * 16) = acc[i][j];
    }
  }
}

// ---------------- combine: out[t] = y[slot0(t)] + y[slot1(t)] ----------------
__global__ __launch_bounds__(256) void combine_kernel(
    const float* __restrict__ y, const int* __restrict__ inv,
    const int* __restrict__ offs, float* __restrict__ out) {
  const int idx = blockIdx.x * 256 + threadIdx.x;   // over TOKENS*512 float4s
  const int tkn = idx >> 9, q = idx & 511;
  const int v0 = inv[tkn * 2], v1 = inv[tkn * 2 + 1];
  const size_t r0 = (size_t)(offs[v0 >> 12] + (v0 & 4095));
  const size_t r1 = (size_t)(offs[v1 >> 12] + (v1 & 4095));
  const float4 a = ((const float4*)y)[r0 * 512 + q];
  const float4 b = ((const float4*)y)[r1 * 512 + q];
  float4 o; o.x = a.x + b.x; o.y = a.y + b.y; o.z = a.z + b.z; o.w = a.w + b.w;
  ((float4*)out)[idx] = o;
}

extern "C" void kernel_launch(void* const* d_in, const int* in_sizes, int n_in,
                              void* d_out, int out_size, void* d_ws, size_t ws_size,
                              hipStream_t stream) {
  const float* x  = (const float*)d_in[0];
  const float* rw = (const float*)d_in[1];
  const float* wg = (const float*)d_in[2];
  const float* wu = (const float*)d_in[3];
  const float* wd = (const float*)d_in[4];
  float* out = (float*)d_out;

  char* ws = (char*)d_ws;
  size_t o = 0;
  auto alloc = [&](size_t b) { void* p = ws + o; o += (b + 255) & ~(size_t)255; return p; };
  int*   cnt  = (int*)alloc(NE * 4);
  int*   offs = (int*)alloc((NE + 1) * 4);
  int*   tok  = (int*)alloc((size_t)NE * 4096 * 4);
  float* wts  = (float*)alloc((size_t)NE * 4096 * 4);
  int*   inv  = (int*)alloc((size_t)TOKENS * 2 * 4);
  bf16*  xb   = (bf16*)alloc((size_t)TOKENS * HIDDEN * 2);
  bf16*  wgu  = (bf16*)alloc((size_t)NE * NGU * HIDDEN * 2);
  bf16*  wdt  = (bf16*)alloc((size_t)NE * HIDDEN * INTER * 2);
  bf16*  h    = (bf16*)alloc((size_t)CAP_ROWS * INTER * 2);
  // ybuf (75.5 MB) aliases wgu (92.3 MB): wgu dead after gemm_gateup, stream-ordered.
  float* ybuf = (float*)wgu;

  hipMemsetAsync(cnt, 0, NE * 4, stream);

  router_kernel<<<TOKENS / 4, 256, 0, stream>>>(x, rw, xb, cnt, tok, wts, inv);
  scan_kernel<<<1, 64, 0, stream>>>(cnt, offs);

  prep_weights<<<dim3(3 * 5632), 256, 0, stream>>>(wg, wu, wd, wgu, wdt);

  gemm_gateup<<<dim3(NE * (TOKENS / 128) * (NGU / 128)), 256, 0, stream>>>(
      xb, wgu, h, cnt, offs, tok, wts);
  gemm_down<<<dim3(NE * (TOKENS / 128) * (HIDDEN / 128)), 256, 0, stream>>>(
      h, wdt, ybuf, cnt, offs);
  combine_kernel<<<dim3(TOKENS * (HIDDEN / 4) / 256), 256, 0, stream>>>(
      ybuf, inv, offs, out);
}

// Round 4
// 640.532 us; speedup vs baseline: 1.0894x; 1.0592x over previous
//
#include <hip/hip_runtime.h>
#include <hip/hip_bf16.h>
#include <cstdint>
#include <cstddef>

#define TOKENS 4096
#define HIDDEN 2048
#define INTER  1408
#define NE     8
#define NGU    2816            // 2*INTER (gate | up, 16-col interleaved)
#define CAP_ROWS 9216          // >= 8192 assignments + 8*127 tile pad

typedef __bf16 bf16;
typedef __bf16 bf16x8 __attribute__((ext_vector_type(8)));
typedef __bf16 bf16x4 __attribute__((ext_vector_type(4)));
typedef float  f32x4  __attribute__((ext_vector_type(4)));

__device__ __forceinline__ void async16(const void* g, void* l) {
  __builtin_amdgcn_global_load_lds((const __attribute__((address_space(1))) void*)g,
                                   (__attribute__((address_space(3))) void*)l,
                                   16, 0, 0);
}

// ---------------- router: logits, top-2, renorm weights; also x -> bf16 ----------------
__global__ void router_kernel(const float* __restrict__ x, const float* __restrict__ rw,
                              bf16* __restrict__ xb, int* __restrict__ cnt,
                              int* __restrict__ tok, float* __restrict__ wts,
                              int* __restrict__ inv) {
  const int w = threadIdx.x >> 6, l = threadIdx.x & 63;
  const int t = blockIdx.x * 4 + w;
  const float4* x4 = (const float4*)(x + (size_t)t * HIDDEN);
  const float4* r4 = (const float4*)rw;
  float acc[NE];
#pragma unroll
  for (int e = 0; e < NE; ++e) acc[e] = 0.f;
#pragma unroll
  for (int c = 0; c < 8; ++c) {
    const int idx = c * 64 + l;
    const float4 v = x4[idx];
    bf16* dst = xb + (size_t)t * HIDDEN + idx * 4;
    dst[0] = (bf16)v.x; dst[1] = (bf16)v.y; dst[2] = (bf16)v.z; dst[3] = (bf16)v.w;
#pragma unroll
    for (int e = 0; e < NE; ++e) {
      const float4 u = r4[e * 512 + idx];
      acc[e] += v.x * u.x + v.y * u.y + v.z * u.z + v.w * u.w;
    }
  }
#pragma unroll
  for (int e = 0; e < NE; ++e)
#pragma unroll
    for (int s = 32; s > 0; s >>= 1) acc[e] += __shfl_xor(acc[e], s, 64);
  if (l == 0) {
    int i0 = 0; float l0 = acc[0];
#pragma unroll
    for (int e = 1; e < NE; ++e) if (acc[e] > l0) { l0 = acc[e]; i0 = e; }
    int i1 = -1; float l1 = -3.4e38f;
#pragma unroll
    for (int e = 0; e < NE; ++e) if (e != i0 && acc[e] > l1) { l1 = acc[e]; i1 = e; }
    const float w0 = 1.f / (1.f + __expf(l1 - l0));
    const float w1 = 1.f - w0;
    int p = atomicAdd(&cnt[i0], 1);
    tok[i0 * 4096 + p] = t; wts[i0 * 4096 + p] = w0; inv[t * 2]     = (i0 << 12) | p;
    p = atomicAdd(&cnt[i1], 1);
    tok[i1 * 4096 + p] = t; wts[i1 * 4096 + p] = w1; inv[t * 2 + 1] = (i1 << 12) | p;
  }
}

// ---------------- 128-aligned exclusive scan of expert counts (8 entries) ----------------
__global__ void scan_kernel(const int* __restrict__ cnt, int* __restrict__ offs) {
  if (threadIdx.x == 0 && blockIdx.x == 0) {
    int o = 0;
    for (int e = 0; e < NE; ++e) { offs[e] = o; o += ((cnt[e] + 127) >> 7) << 7; }
    offs[NE] = o;
  }
}

// ---------------- fused weight prep: 3 transposes in one launch ----------------
__global__ __launch_bounds__(256) void prep_weights(
    const float* __restrict__ wg, const float* __restrict__ wu, const float* __restrict__ wd,
    bf16* __restrict__ wgu, bf16* __restrict__ wdt) {
  __shared__ float tile[64][65];
  const int bid = blockIdx.x;
  const int which = bid / 5632;
  const int rem = bid - which * 5632;
  const int e = rem & 7;
  const int tid2 = rem >> 3;          // 0..703
  const float* in; bf16* out; int R, C, c0, r0, mode;
  if (which == 2) {
    in = wd + (size_t)e * INTER * HIDDEN; out = wdt + (size_t)e * HIDDEN * INTER;
    R = INTER; C = HIDDEN; c0 = (tid2 & 31) * 64; r0 = (tid2 >> 5) * 64; mode = 0;
  } else {
    in = (which ? wu : wg) + (size_t)e * HIDDEN * INTER; out = wgu + (size_t)e * NGU * HIDDEN;
    R = HIDDEN; C = INTER; c0 = (tid2 % 22) * 64; r0 = (tid2 / 22) * 64; mode = which + 1;
  }
  const int t = threadIdx.x;
  const int row = t >> 4, cq = t & 15;
  const float* src = in + (size_t)(r0 + row) * C + c0 + cq * 4;
#pragma unroll
  for (int p = 0; p < 4; ++p) {
    const float4 v = *(const float4*)(src + (size_t)(p * 16) * C);
    *(float4*)&tile[p * 16 + row][cq * 4] = v;
  }
  __syncthreads();
  const int oc = t >> 2, rq = t & 3;
  float vals[16];
#pragma unroll
  for (int i = 0; i < 16; ++i) vals[i] = tile[rq * 16 + i][oc];
  const int c = c0 + oc;
  int p;
  if (mode == 0) p = c;
  else p = ((c >> 4) << 5) + (c & 15) + (mode == 2 ? 16 : 0);
  bf16x8 o0, o1;
#pragma unroll
  for (int i = 0; i < 8; ++i) { o0[i] = (bf16)vals[i]; o1[i] = (bf16)vals[8 + i]; }
  bf16* dst = out + (size_t)p * R + r0 + rq * 16;
  *(bf16x8*)dst = o0;
  *(bf16x8*)(dst + 8) = o1;
}

// ---------------- GEMM1: persistent XCD-pinned blocks, gathered X x [Wg|Wu]^T -> H ----------------
// grid = 2048 (8 blocks/CU target). e = bid&7 (expert==XCD); slot = bid>>3 strides the
// expert's REAL tile list (no dead blocks). 1-phase K-loop (verified); swapped mfma operands
// put N on the D-row dim -> vectorized epilogue stores.
__global__ __launch_bounds__(256, 4) void gemm_gateup(
    const bf16* __restrict__ X, const bf16* __restrict__ W, bf16* __restrict__ H,
    const int* __restrict__ cnt, const int* __restrict__ offs,
    const int* __restrict__ tok, const float* __restrict__ wts) {
  const int e = blockIdx.x & 7;
  const int slot = blockIdx.x >> 3;            // 0..255 per expert
  const int c = cnt[e];
  if (c == 0) return;
  const int mtiles = (c + 127) >> 7;
  const int total = mtiles * (NGU / 128);      // real tiles only

  __shared__ bf16 sA[128 * 32];
  __shared__ bf16 sB[128 * 32];

  const int t = threadIdx.x, l = t & 63, w = t >> 6;
  const int iA0 = t, iA1 = t + 256;
  const int rA0 = iA0 >> 2, g0 = iA0 & 3;
  const int rA1 = iA1 >> 2, g1 = iA1 & 3;
  bf16* la0 = sA + iA0 * 8; bf16* la1 = sA + iA1 * 8;
  bf16* lb0 = sB + iA0 * 8; bf16* lb1 = sB + iA1 * 8;

  const int wm = (w >> 1) * 64, wn = (w & 1) * 64;
  const int r16 = l & 15, quad = l >> 4;
  const bf16* fA = sA + (wm + r16) * 32 + quad * 8;
  const bf16* fB = sB + (wn + r16) * 32 + quad * 8;

  for (int it = slot; it < total; it += 256) {
    const int mt = it % mtiles;                // mt fastest: B-panel reuse within XCD
    const int nt = it / mtiles;

    const int gr0 = tok[e * 4096 + (mt * 128 + rA0 < c ? mt * 128 + rA0 : c - 1)];
    const int gr1 = tok[e * 4096 + (mt * 128 + rA1 < c ? mt * 128 + rA1 : c - 1)];
    const bf16* pa0 = X + (size_t)gr0 * HIDDEN + g0 * 8;
    const bf16* pa1 = X + (size_t)gr1 * HIDDEN + g1 * 8;
    const bf16* pb0 = W + ((size_t)e * NGU + nt * 128 + rA0) * HIDDEN + g0 * 8;
    const bf16* pb1 = W + ((size_t)e * NGU + nt * 128 + rA1) * HIDDEN + g1 * 8;

    f32x4 acc[4][4];
#pragma unroll
    for (int i = 0; i < 4; ++i)
#pragma unroll
      for (int j = 0; j < 4; ++j) acc[i][j] = (f32x4){0.f, 0.f, 0.f, 0.f};

    for (int kk = 0; kk < HIDDEN; kk += 32) {
      async16(pa0 + kk, la0); async16(pa1 + kk, la1);
      async16(pb0 + kk, lb0); async16(pb1 + kk, lb1);
      __syncthreads();
      bf16x8 a[4], b[4];
#pragma unroll
      for (int i = 0; i < 4; ++i) a[i] = *(const bf16x8*)(fA + i * 16 * 32);
#pragma unroll
      for (int j = 0; j < 4; ++j) b[j] = *(const bf16x8*)(fB + j * 16 * 32);
#pragma unroll
      for (int i = 0; i < 4; ++i)
#pragma unroll
        for (int j = 0; j < 4; ++j)
          acc[i][j] = __builtin_amdgcn_mfma_f32_16x16x32_bf16(b[j], a[i], acc[i][j], 0, 0, 0);
      __syncthreads();
    }

    // swapped layout: lane holds n = wn + j*16 + quad*4 + r, m = wm + i*16 + r16
    const int mRowBase = mt * 128 + wm + r16;
    const int hcolBase = nt * 64 + (wn >> 1) + quad * 4;
#pragma unroll
    for (int i = 0; i < 4; ++i) {
      const int m = mRowBase + i * 16;
      const int mc = m < c ? m : c - 1;
      const float ws = wts[e * 4096 + mc];
      bf16* rowp = H + (size_t)(offs[e] + m) * INTER;
#pragma unroll
      for (int jp = 0; jp < 2; ++jp) {
        bf16x4 hv;
#pragma unroll
        for (int r = 0; r < 4; ++r) {
          const float g = acc[i][2 * jp][r];
          const float u = acc[i][2 * jp + 1][r];
          hv[r] = (bf16)((g / (1.f + __expf(-g))) * u * ws);
        }
        *(bf16x4*)(rowp + hcolBase + jp * 16) = hv;
      }
    }
  }
}

// ---------------- GEMM2: persistent blocks, H x Wdown^T -> ybuf rows (no atomics) ----------------
__global__ __launch_bounds__(256, 4) void gemm_down(
    const bf16* __restrict__ Hin, const bf16* __restrict__ W, float* __restrict__ ybuf,
    const int* __restrict__ cnt, const int* __restrict__ offs) {
  const int e = blockIdx.x & 7;
  const int slot = blockIdx.x >> 3;
  const int c = cnt[e];
  if (c == 0) return;
  const int mtiles = (c + 127) >> 7;
  const int total = mtiles * (HIDDEN / 128);

  __shared__ bf16 sA[128 * 32];
  __shared__ bf16 sB[128 * 32];

  const int t = threadIdx.x, l = t & 63, w = t >> 6;
  const int iA0 = t, iA1 = t + 256;
  const int rA0 = iA0 >> 2, g0 = iA0 & 3;
  const int rA1 = iA1 >> 2, g1 = iA1 & 3;
  bf16* la0 = sA + iA0 * 8; bf16* la1 = sA + iA1 * 8;
  bf16* lb0 = sB + iA0 * 8; bf16* lb1 = sB + iA1 * 8;

  const int wm = (w >> 1) * 64, wn = (w & 1) * 64;
  const int r16 = l & 15, quad = l >> 4;
  const bf16* fA = sA + (wm + r16) * 32 + quad * 8;
  const bf16* fB = sB + (wn + r16) * 32 + quad * 8;

  for (int it = slot; it < total; it += 256) {
    const int mt = it % mtiles;
    const int nt = it / mtiles;

    const int base = offs[e] + mt * 128;
    const bf16* pa0 = Hin + (size_t)(base + rA0) * INTER + g0 * 8;
    const bf16* pa1 = Hin + (size_t)(base + rA1) * INTER + g1 * 8;
    const bf16* pb0 = W + ((size_t)e * HIDDEN + nt * 128 + rA0) * INTER + g0 * 8;
    const bf16* pb1 = W + ((size_t)e * HIDDEN + nt * 128 + rA1) * INTER + g1 * 8;

    f32x4 acc[4][4];
#pragma unroll
    for (int i = 0; i < 4; ++i)
#pragma unroll
      for (int j = 0; j < 4; ++j) acc[i][j] = (f32x4){0.f, 0.f, 0.f, 0.f};

    for (int kk = 0; kk < INTER; kk += 32) {
      async16(pa0 + kk, la0); async16(pa1 + kk, la1);
      async16(pb0 + kk, lb0); async16(pb1 + kk, lb1);
      __syncthreads();
      bf16x8 a[4], b[4];
#pragma unroll
      for (int i = 0; i < 4; ++i) a[i] = *(const bf16x8*)(fA + i * 16 * 32);
#pragma unroll
      for (int j = 0; j < 4; ++j) b[j] = *(const bf16x8*)(fB + j * 16 * 32);
#pragma unroll
      for (int i = 0; i < 4; ++i)
#pragma unroll
        for (int j = 0; j < 4; ++j)
          acc[i][j] = __builtin_amdgcn_mfma_f32_16x16x32_bf16(b[j], a[i], acc[i][j], 0, 0, 0);
      __syncthreads();
    }

    const int mRowBase = mt * 128 + wm + r16;
    const int colBase = nt * 128 + wn + quad * 4;
#pragma unroll
    for (int i = 0; i < 4; ++i) {
      const int m = mRowBase + i * 16;
      if (m < c) {
        float* rowp = ybuf + (size_t)(offs[e] + m) * HIDDEN + colBase;
#pragma unroll
        for (int j = 0; j < 4; ++j)
          *(f32x4*)(rowp + j * 16) = acc[i][j];
      }
    }
  }
}

// ---------------- combine: out[t] = y[slot0(t)] + y[slot1(t)] ----------------
__global__ __launch_bounds__(256) void combine_kernel(
    const float* __restrict__ y, const int* __restrict__ inv,
    const int* __restrict__ offs, float* __restrict__ out) {
  const int idx = blockIdx.x * 256 + threadIdx.x;   // over TOKENS*512 float4s
  const int tkn = idx >> 9, q = idx & 511;
  const int v0 = inv[tkn * 2], v1 = inv[tkn * 2 + 1];
  const size_t r0 = (size_t)(offs[v0 >> 12] + (v0 & 4095));
  const size_t r1 = (size_t)(offs[v1 >> 12] + (v1 & 4095));
  const float4 a = ((const float4*)y)[r0 * 512 + q];
  const float4 b = ((const float4*)y)[r1 * 512 + q];
  float4 o; o.x = a.x + b.x; o.y = a.y + b.y; o.z = a.z + b.z; o.w = a.w + b.w;
  ((float4*)out)[idx] = o;
}

extern "C" void kernel_launch(void* const* d_in, const int* in_sizes, int n_in,
                              void* d_out, int out_size, void* d_ws, size_t ws_size,
                              hipStream_t stream) {
  const float* x  = (const float*)d_in[0];
  const float* rw = (const float*)d_in[1];
  const float* wg = (const float*)d_in[2];
  const float* wu = (const float*)d_in[3];
  const float* wd = (const float*)d_in[4];
  float* out = (float*)d_out;

  char* ws = (char*)d_ws;
  size_t o = 0;
  auto alloc = [&](size_t b) { void* p = ws + o; o += (b + 255) & ~(size_t)255; return p; };
  int*   cnt  = (int*)alloc(NE * 4);
  int*   offs = (int*)alloc((NE + 1) * 4);
  int*   tok  = (int*)alloc((size_t)NE * 4096 * 4);
  float* wts  = (float*)alloc((size_t)NE * 4096 * 4);
  int*   inv  = (int*)alloc((size_t)TOKENS * 2 * 4);
  bf16*  xb   = (bf16*)alloc((size_t)TOKENS * HIDDEN * 2);
  bf16*  wgu  = (bf16*)alloc((size_t)NE * NGU * HIDDEN * 2);
  bf16*  wdt  = (bf16*)alloc((size_t)NE * HIDDEN * INTER * 2);
  bf16*  h    = (bf16*)alloc((size_t)CAP_ROWS * INTER * 2);
  // ybuf (75.5 MB) aliases wgu (92.3 MB): wgu dead after gemm_gateup, stream-ordered.
  float* ybuf = (float*)wgu;

  hipMemsetAsync(cnt, 0, NE * 4, stream);

  router_kernel<<<TOKENS / 4, 256, 0, stream>>>(x, rw, xb, cnt, tok, wts, inv);
  scan_kernel<<<1, 64, 0, stream>>>(cnt, offs);

  prep_weights<<<dim3(3 * 5632), 256, 0, stream>>>(wg, wu, wd, wgu, wdt);

  gemm_gateup<<<dim3(2048), 256, 0, stream>>>(xb, wgu, h, cnt, offs, tok, wts);
  gemm_down<<<dim3(2048), 256, 0, stream>>>(h, wdt, ybuf, cnt, offs);
  combine_kernel<<<dim3(TOKENS * (HIDDEN / 4) / 256), 256, 0, stream>>>(
      ybuf, inv, offs, out);
}